// Round 8
// baseline (79.974 us; speedup 1.0000x reference)
//
#include <hip/hip_runtime.h>
#include <stdint.h>

#define NB 8
#define NT 2048
#define NC 1024
#define HD 64

typedef __attribute__((ext_vector_type(8)))  short s16x8;
typedef __attribute__((ext_vector_type(4)))  float f32x4;
typedef __attribute__((ext_vector_type(16))) float f32x16;

__device__ inline ushort f2b(float f) {
    union { float f; uint32_t u; } c; c.f = f;
    uint32_t u = c.u;
    uint32_t r = (u + 0x7fffu + ((u >> 16) & 1u)) >> 16;   // RNE, finite inputs
    return (ushort)r;
}

__device__ inline uint32_t cvt_pk_bf16(float lo, float hi) {
    uint32_t r;
    asm("v_cvt_pk_bf16_f32 %0, %1, %2" : "=v"(r) : "v"(lo), "v"(hi));
    return r;
}

__device__ inline void gload_lds16(const void* gsrc, void* lds) {
    __builtin_amdgcn_global_load_lds(
        (const __attribute__((address_space(1))) void*)gsrc,
        (__attribute__((address_space(3))) void*)lds, 16, 0, 0);
}

// ---------------------------------------------------------------------------
// Kernel 0: W [1024][192] f32  ->  Wt [192][1024] bf16, q-cols pre-scaled by
// 0.125 * log2(e) so attention logits are already base-2.
// ---------------------------------------------------------------------------
__global__ __launch_bounds__(256) void wprep(const float* __restrict__ W,
                                             ushort* __restrict__ wt) {
    int tid = blockIdx.x * 256 + threadIdx.x;   // 192*1024 total
    int n = tid >> 10;          // 0..191 (output col of qkv)
    int k = tid & 1023;         // 0..1023
    float v = W[k * 192 + n];
    if (n < 64) v *= 0.125f * 1.4426950408889634f;
    wt[n * 1024 + k] = f2b(v);
}

// ---------------------------------------------------------------------------
// Kernel 1: qkv = x @ W.  BARRIER-FREE K-loop.
// Block: 256 rows x 48 cols, 8 waves (wave = 32 rows x 48 cols), grid 256
// (1 block/CU), 4 col-groups x 64 row-tiles.
// W-slice (48 cols x K=1024 bf16 = 96 KB) staged ONCE into LDS at block
// start (layout [k8=k/8][64 slots][16B], structural-min bank spread), then
// the 16-step K-loop has NO barriers / NO staging / NO manual waitcnt:
// each wave streams its A-rows from global f32 (fully unrolled, all offsets
// compile-time imm, 2-steps-ahead explicit prefetch in 16 statically-indexed
// float4 regs), converts via cvt_pk, reads B from read-only LDS, MFMAs.
// Waves drift out of phase -> loads/LDS/MFMA overlap across the CU.
// ---------------------------------------------------------------------------
__global__ __launch_bounds__(512, 2) void qkv_gemm(const float* __restrict__ x,
                                                   const ushort* __restrict__ wt,
                                                   ushort* __restrict__ qs,
                                                   ushort* __restrict__ kk,
                                                   ushort* __restrict__ vt) {
    __shared__ __align__(16) char Wl[131072];   // [k8 0..127][slot 0..63][16B]

    const int tid = threadIdx.x;
    const int wv  = tid >> 6;         // 0..7
    const int ls  = tid & 63;
    const int r16 = ls & 15;
    const int hi4 = ls >> 4;          // 0..3
    const int bid = blockIdx.x;
    const int cg  = bid & 3;          // col-group: cols cg*48 .. +48
    const int row0 = (bid >> 2) * 256;

    // ---- one-time W-slice stage: 16 gload_lds16 per wave ----
    {
        int nsrc = cg * 48 + ls;
        if (nsrc > 191) nsrc = 191;               // lanes 48..63: dummy rows
        const ushort* wsrc = wt + (size_t)nsrc * 1024;
#pragma unroll
        for (int j = 0; j < 16; ++j) {
            int k8 = wv * 16 + j;
            gload_lds16(wsrc + k8 * 8, &Wl[k8 * 1024]);
        }
    }

    // ---- A pointers (per-lane rows; all loop offsets are compile-time) ----
    const float* pA0 = x + (size_t)(row0 + wv * 32 + 0  + r16) * NC + hi4 * 8;
    const float* pA1 = x + (size_t)(row0 + wv * 32 + 16 + r16) * NC + hi4 * 8;

    // A prefetch regs: [set][m][kq][half], statically indexed under unroll
    float4 ab[2][2][2][2];

#define LOADA(S, T)                                                          \
    do {                                                                     \
        _Pragma("unroll")                                                    \
        for (int kq_ = 0; kq_ < 2; ++kq_) {                                  \
            _Pragma("unroll")                                                \
            for (int h_ = 0; h_ < 2; ++h_) {                                 \
                ab[S][0][kq_][h_] = *(const float4*)(pA0 + (T) * 64 + kq_ * 32 + h_ * 4); \
                ab[S][1][kq_][h_] = *(const float4*)(pA1 + (T) * 64 + kq_ * 32 + h_ * 4); \
            }                                                                \
        }                                                                    \
    } while (0)

    LOADA(0, 0);
    LOADA(1, 1);

    f32x4 acc[2][3];
#pragma unroll
    for (int i = 0; i < 2; ++i)
#pragma unroll
        for (int j = 0; j < 3; ++j)
#pragma unroll
            for (int e = 0; e < 4; ++e) acc[i][j][e] = 0.f;

    // one-time drain: W image + first two A sets resident
    asm volatile("s_waitcnt vmcnt(0)" ::: "memory");
    __builtin_amdgcn_s_barrier();

    // ---- barrier-free K-loop: 16 steps, fully unrolled ----
#pragma unroll
    for (int t = 0; t < 16; ++t) {
        const int set = t & 1;
        // convert current set to bf16 A-frags
        s16x8 af[2][2];
#pragma unroll
        for (int m = 0; m < 2; ++m)
#pragma unroll
            for (int kq = 0; kq < 2; ++kq) {
                float4 a0 = ab[set][m][kq][0];
                float4 a1 = ab[set][m][kq][1];
                union { uint32_t w[4]; s16x8 v; } pk;
                pk.w[0] = cvt_pk_bf16(a0.x, a0.y);
                pk.w[1] = cvt_pk_bf16(a0.z, a0.w);
                pk.w[2] = cvt_pk_bf16(a1.x, a1.y);
                pk.w[3] = cvt_pk_bf16(a1.z, a1.w);
                af[m][kq] = pk.v;
            }
        // refill this set for step t+2 (stays ~2 iterations in flight)
        if (t + 2 < 16) LOADA(set, t + 2);
        __builtin_amdgcn_sched_barrier(0);   // pin: loads issued before compute
        // B-frags from LDS + MFMA
#pragma unroll
        for (int kq = 0; kq < 2; ++kq) {
            const int k8 = t * 8 + kq * 4 + hi4;
            s16x8 bf[3];
#pragma unroll
            for (int nf = 0; nf < 3; ++nf)
                bf[nf] = *(const s16x8*)(&Wl[k8 * 1024 + (nf * 16 + r16) * 16]);
#pragma unroll
            for (int m = 0; m < 2; ++m)
#pragma unroll
                for (int nf = 0; nf < 3; ++nf)
                    acc[m][nf] = __builtin_amdgcn_mfma_f32_16x16x32_bf16(
                        af[m][kq], bf[nf], acc[m][nf], 0, 0, 0);
        }
    }
#undef LOADA

    // ---- epilogue: scatter to qs / kk / vt(bf16, transposed) ----
    const int b = row0 >> 11;
#pragma unroll
    for (int m = 0; m < 2; ++m) {
        const int rbase = row0 + wv * 32 + m * 16 + hi4 * 4;
#pragma unroll
        for (int nf = 0; nf < 3; ++nf) {
            int colg = cg * 48 + nf * 16 + r16;   // 0..191
            f32x4 v = acc[m][nf];
            if (colg < 64) {
#pragma unroll
                for (int j = 0; j < 4; ++j)
                    qs[(size_t)(rbase + j) * HD + colg] = f2b(v[j]);
            } else if (colg < 128) {
#pragma unroll
                for (int j = 0; j < 4; ++j)
                    kk[(size_t)(rbase + j) * HD + (colg - 64)] = f2b(v[j]);
            } else {
                int d = colg - 128;
                union { ushort4 s; ushort u[4]; } pk;
#pragma unroll
                for (int j = 0; j < 4; ++j) pk.u[j] = f2b(v[j]);
                *(ushort4*)(&vt[((size_t)(b * 64 + d)) * NT + (rbase & (NT - 1))]) = pk.s;
            }
        }
    }
}

// ---------------------------------------------------------------------------
// Kernel 2: causal flash attention. 4 waves/block, intra-block split-K:
// wave w handles k-tiles w, w+4, ... of its 32-row q-tile; partial
// (m,l,o) merged in LDS with exp2 rescaling. grid = 512, big tiles first.
// ---------------------------------------------------------------------------
__global__ __launch_bounds__(256) void attn(const ushort* __restrict__ qs,
                                            const ushort* __restrict__ kk,
                                            const ushort* __restrict__ vt,
                                            float* __restrict__ out) {
    __shared__ float ob[4][64][33];   // per-wave unnormalized O^T partials
    __shared__ float ml[4][2][32];    // per-wave m / lsum per q col

    const int bid  = blockIdx.x;
    const int b    = bid & 7;
    const int tile = 63 - (bid >> 3);          // big-first for balance
    const int tid  = threadIdx.x;
    const int wv   = tid >> 6;                 // 0..3  (k-split index)
    const int l    = tid & 63;
    const int qcol = l & 31;
    const int hi   = l >> 5;
    const int r0   = tile * 32;

    const ushort* qb = qs + ((size_t)(b * NT + r0)) * HD;
    const ushort* kb = kk + (size_t)b * NT * HD;
    const ushort* vb = vt + (size_t)b * HD * NT;

    s16x8 qf[4];
#pragma unroll
    for (int c = 0; c < 4; ++c)
        qf[c] = *(const s16x8*)(qb + (size_t)qcol * HD + c * 16 + hi * 8);

    f32x16 o0, o1;
#pragma unroll
    for (int i = 0; i < 16; ++i) { o0[i] = 0.f; o1[i] = 0.f; }
    float m = -3.0e30f, lsum = 0.f;

    if (wv <= tile) {
        s16x8 kf[4], vf[4];
        {
            const ushort* kr = kb + (size_t)(wv * 32 + qcol) * HD;
#pragma unroll
            for (int c = 0; c < 4; ++c)
                kf[c] = *(const s16x8*)(kr + c * 16 + hi * 8);
#pragma unroll
            for (int dt = 0; dt < 2; ++dt)
#pragma unroll
                for (int kc = 0; kc < 2; ++kc)
                    vf[dt * 2 + kc] = *(const s16x8*)(vb + (size_t)(dt * 32 + qcol) * NT
                                                      + wv * 32 + kc * 16 + hi * 8);
        }

        for (int kt = wv; kt <= tile; kt += 4) {
            // S^T = K . Q^T   (col = q, row-regs = k_local)
            f32x16 s;
#pragma unroll
            for (int i = 0; i < 16; ++i) s[i] = 0.f;
#pragma unroll
            for (int c = 0; c < 4; ++c)
                s = __builtin_amdgcn_mfma_f32_32x32x16_bf16(kf[c], qf[c], s, 0, 0, 0);

            // prefetch this wave's next K/V tiles (stride 4)
            s16x8 kfn[4], vfn[4];
            const bool more = (kt + 4 <= tile);
            if (more) {
                const ushort* kr = kb + (size_t)((kt + 4) * 32 + qcol) * HD;
#pragma unroll
                for (int c = 0; c < 4; ++c)
                    kfn[c] = *(const s16x8*)(kr + c * 16 + hi * 8);
#pragma unroll
                for (int dt = 0; dt < 2; ++dt)
#pragma unroll
                    for (int kc = 0; kc < 2; ++kc)
                        vfn[dt * 2 + kc] = *(const s16x8*)(vb + (size_t)(dt * 32 + qcol) * NT
                                                           + (kt + 4) * 32 + kc * 16 + hi * 8);
            }

            // online softmax (per-lane scalar state: one q per lane)
            const bool diag = (kt == tile);
            float p[16];
#pragma unroll
            for (int r = 0; r < 16; ++r) {
                int klocal = (r & 3) + 8 * (r >> 2) + 4 * hi;
                float sv = s[r];
                if (diag && klocal > qcol) sv = -3.0e30f;
                p[r] = sv;
            }
            float pmax = p[0];
#pragma unroll
            for (int r = 1; r < 16; ++r) pmax = fmaxf(pmax, p[r]);
            pmax = fmaxf(pmax, __shfl_xor(pmax, 32));
            float mnew = fmaxf(m, pmax);
            float corr = exp2f(m - mnew);
            m = mnew;
            float rs = 0.f;
#pragma unroll
            for (int r = 0; r < 16; ++r) { p[r] = exp2f(p[r] - mnew); rs += p[r]; }
            rs += __shfl_xor(rs, 32);
            lsum = lsum * corr + rs;
#pragma unroll
            for (int i = 0; i < 16; ++i) { o0[i] *= corr; o1[i] *= corr; }

            // P (f32, S^T layout) -> bf16 B-fragments via cvt_pk + lane^32 exchange
#pragma unroll
            for (int kc = 0; kc < 2; ++kc) {
                int pb = kc * 8;
                uint32_t a0 = cvt_pk_bf16(p[pb + 0], p[pb + 1]);
                uint32_t a1 = cvt_pk_bf16(p[pb + 2], p[pb + 3]);
                uint32_t b0 = cvt_pk_bf16(p[pb + 4], p[pb + 5]);
                uint32_t b1 = cvt_pk_bf16(p[pb + 6], p[pb + 7]);
                uint32_t a0x = __shfl_xor(a0, 32);
                uint32_t a1x = __shfl_xor(a1, 32);
                uint32_t b0x = __shfl_xor(b0, 32);
                uint32_t b1x = __shfl_xor(b1, 32);
                union { uint32_t w[4]; s16x8 v; } frag;
                frag.w[0] = hi ? b0x : a0;
                frag.w[1] = hi ? b1x : a1;
                frag.w[2] = hi ? b0  : a0x;
                frag.w[3] = hi ? b1  : a1x;
                o0 = __builtin_amdgcn_mfma_f32_32x32x16_bf16(vf[0 * 2 + kc], frag.v, o0, 0, 0, 0);
                o1 = __builtin_amdgcn_mfma_f32_32x32x16_bf16(vf[1 * 2 + kc], frag.v, o1, 0, 0, 0);
            }

            if (more) {
#pragma unroll
                for (int c = 0; c < 4; ++c) kf[c] = kfn[c];
#pragma unroll
                for (int c = 0; c < 4; ++c) vf[c] = vfn[c];
            }
        }
    }

    // --- write per-wave partials (unnormalized) ---
#pragma unroll
    for (int r = 0; r < 16; ++r) {
        int d = (r & 3) + 8 * (r >> 2) + 4 * hi;
        ob[wv][d][qcol]      = o0[r];
        ob[wv][d + 32][qcol] = o1[r];
    }
    if (hi == 0) {
        ml[wv][0][qcol] = m;
        ml[wv][1][qcol] = lsum;
    }
    __syncthreads();

    // --- merge 4 partials + coalesced f32 store ---
    // thread -> (q = tid>>3, d block of 8 at (tid&7)*8)
    const int q  = tid >> 3;
    const int j0 = (tid & 7) * 8;
    float mw[4];
#pragma unroll
    for (int w = 0; w < 4; ++w) mw[w] = ml[w][0][q];
    float M = fmaxf(fmaxf(mw[0], mw[1]), fmaxf(mw[2], mw[3]));
    float sw[4]; float L = 0.f;
#pragma unroll
    for (int w = 0; w < 4; ++w) {
        sw[w] = exp2f(mw[w] - M);
        L += sw[w] * ml[w][1][q];
    }
    float invL = 1.0f / L;
    float vals[8];
#pragma unroll
    for (int j = 0; j < 8; ++j) {
        int d = j0 + j;
        float acc = 0.f;
#pragma unroll
        for (int w = 0; w < 4; ++w) acc += sw[w] * ob[w][d][q];
        vals[j] = acc * invL;
    }
    float* orow = out + ((size_t)(b * NT + r0 + q)) * HD + j0;
    *(float4*)(orow)     = make_float4(vals[0], vals[1], vals[2], vals[3]);
    *(float4*)(orow + 4) = make_float4(vals[4], vals[5], vals[6], vals[7]);
}

// ---------------------------------------------------------------------------
extern "C" void kernel_launch(void* const* d_in, const int* in_sizes, int n_in,
                              void* d_out, int out_size, void* d_ws, size_t ws_size,
                              hipStream_t stream) {
    const float* x = (const float*)d_in[0];
    const float* W = (const float*)d_in[1];
    float* out = (float*)d_out;

    ushort* qs = (ushort*)d_ws;                 // [8][2048][64] bf16 (pre-scaled q)
    ushort* kk = qs + (size_t)NB * NT * HD;     // [8][2048][64]
    ushort* vt = kk + (size_t)NB * NT * HD;     // [8][64][2048]  (V transposed)
    ushort* wt = vt + (size_t)NB * NT * HD;     // [192][1024]    (W^T bf16)

    wprep<<<768, 256, 0, stream>>>(W, wt);
    qkv_gemm<<<256, 512, 0, stream>>>(x, wt, qs, kk, vt);
    attn<<<512, 256, 0, stream>>>(qs, kk, vt, out);
}

// Round 9
// 54.201 us; speedup vs baseline: 1.4755x; 1.4755x over previous
//
#include <hip/hip_runtime.h>
#include <stdint.h>

#define NB 8
#define NT 2048
#define NC 1024
#define HD 64

typedef __attribute__((ext_vector_type(8)))  short s16x8;
typedef __attribute__((ext_vector_type(4)))  float f32x4;
typedef __attribute__((ext_vector_type(16))) float f32x16;

__device__ inline ushort f2b(float f) {
    union { float f; uint32_t u; } c; c.f = f;
    uint32_t u = c.u;
    uint32_t r = (u + 0x7fffu + ((u >> 16) & 1u)) >> 16;   // RNE, finite inputs
    return (ushort)r;
}

__device__ inline uint32_t cvt_pk_bf16(float lo, float hi) {
    uint32_t r;
    asm("v_cvt_pk_bf16_f32 %0, %1, %2" : "=v"(r) : "v"(lo), "v"(hi));
    return r;
}

__device__ inline void gload_lds16(const void* gsrc, void* lds) {
    __builtin_amdgcn_global_load_lds(
        (const __attribute__((address_space(1))) void*)gsrc,
        (__attribute__((address_space(3))) void*)lds, 16, 0, 0);
}

// ---------------------------------------------------------------------------
// Kernel 0: W [1024][192] f32  ->  Wt [192][1024] bf16, q-cols pre-scaled by
// 0.125 * log2(e) so attention logits are already base-2.
// ---------------------------------------------------------------------------
__global__ __launch_bounds__(256) void wprep(const float* __restrict__ W,
                                             ushort* __restrict__ wt) {
    int tid = blockIdx.x * 256 + threadIdx.x;   // 192*1024 total
    int n = tid >> 10;          // 0..191 (output col of qkv)
    int k = tid & 1023;         // 0..1023
    float v = W[k * 192 + n];
    if (n < 64) v *= 0.125f * 1.4426950408889634f;
    wt[n * 1024 + k] = f2b(v);
}

// ---------------------------------------------------------------------------
// Kernel 1: qkv = x @ W.  m97-template: BM=64, BN=96 (2 col-groups), BK=64,
// 4 waves, grid 512 = 2 blocks/CU (two independent barrier groups -> cross-
// block overlap). 2 LDS buffers; per K-step: STAGE(t+1) -> COMPUTE(t) ->
// vmcnt(0) -> barrier.  global_load_lds(16B) staging with contiguity-
// preserving swizzle: lane permutation stays within each row's 128/256B span
// (DRAM granules stay contiguous); ds_reads XOR slot^=(row&7) -> <=2-way
// conflicts per quarter-wave.  A stored f32 (cvt_pk on read).
// Wave wv: rows wv*16..+16, all 96 block cols (6 n-frags).
// bid: rowtile = bid & 255, cg = bid >> 8 (round 2 re-reads x from L3).
// ---------------------------------------------------------------------------
__global__ __launch_bounds__(256, 2) void qkv_gemm(const float* __restrict__ x,
                                                   const ushort* __restrict__ wt,
                                                   ushort* __restrict__ qs,
                                                   ushort* __restrict__ kk,
                                                   ushort* __restrict__ vt) {
    __shared__ __align__(16) char Al[2][16384];   // [64 rows][16 slots x 16B]
    __shared__ __align__(16) char Wl[2][12288];   // [96 rows][8 slots x 16B]

    const int tid = threadIdx.x;
    const int wv  = tid >> 6;         // 0..3
    const int ls  = tid & 63;
    const int r16 = ls & 15;
    const int hi4 = ls >> 4;          // 0..3
    const int bid = blockIdx.x;
    const int rowtile = bid & 255;
    const int cg  = bid >> 8;         // 0/1: cols cg*96..+96
    const int row0 = rowtile * 64;

    // ---- A staging sources: 4 instrs/wave, each 4 rows x 256B ----
    // lane l: row = j*4 + (l>>4), slot16 = (l&15) ^ (row&7)  (stays in-row)
    const float* xsrc[4];
#pragma unroll
    for (int j = 0; j < 4; ++j) {
        int r = wv * 16 + j * 4 + (ls >> 4);            // 0..63
        int slot = (ls & 15) ^ (r & 7);
        xsrc[j] = x + (size_t)(row0 + r) * NC + slot * 4;
    }
    // ---- W staging sources: 3 instrs/wave, each 8 rows x 128B ----
    const ushort* wsrc[3];
#pragma unroll
    for (int j = 0; j < 3; ++j) {
        int n = wv * 24 + j * 8 + (ls >> 3);            // 0..95 local col
        int slot = (ls & 7) ^ (n & 7);
        wsrc[j] = wt + (size_t)(cg * 96 + n) * 1024 + slot * 8;
    }

    // ---- ds_read offsets ----
    const int key = r16 & 7;
    const int arow = wv * 16 + r16;                     // LDS A row
    int aoff[2];                                        // per kq; a1 = a0 ^ 16
#pragma unroll
    for (int kq = 0; kq < 2; ++kq)
        aoff[kq] = arow * 256 + (((kq * 8 + hi4 * 2) ^ key) << 4);
    int bnrow[6];
#pragma unroll
    for (int nf = 0; nf < 6; ++nf)
        bnrow[nf] = (nf * 16 + r16) * 128;
    int bkey[2];
#pragma unroll
    for (int kq = 0; kq < 2; ++kq)
        bkey[kq] = (((kq * 4 + hi4) ^ key) << 4);

    f32x4 acc[6];
#pragma unroll
    for (int j = 0; j < 6; ++j)
#pragma unroll
        for (int e = 0; e < 4; ++e) acc[j][e] = 0.f;

    auto STAGE = [&](int t) {
        int bb = t & 1;
        // A: dest linear 1KB per instr
#pragma unroll
        for (int j = 0; j < 4; ++j)
            gload_lds16(xsrc[j] + t * 64, &Al[bb][wv * 4096 + j * 1024]);
#pragma unroll
        for (int j = 0; j < 3; ++j)
            gload_lds16(wsrc[j] + t * 64, &Wl[bb][wv * 3072 + j * 1024]);
    };

    auto COMPUTE = [&](int bb) {
#pragma unroll
        for (int kq = 0; kq < 2; ++kq) {
            float4 a0 = *(const float4*)(&Al[bb][0] + aoff[kq]);
            float4 a1 = *(const float4*)(&Al[bb][0] + (aoff[kq] ^ 16));
            union { uint32_t w[4]; s16x8 v; } pk;
            pk.w[0] = cvt_pk_bf16(a0.x, a0.y);
            pk.w[1] = cvt_pk_bf16(a0.z, a0.w);
            pk.w[2] = cvt_pk_bf16(a1.x, a1.y);
            pk.w[3] = cvt_pk_bf16(a1.z, a1.w);
            s16x8 af = pk.v;
            s16x8 bf[6];
#pragma unroll
            for (int nf = 0; nf < 6; ++nf)
                bf[nf] = *(const s16x8*)(&Wl[bb][0] + bnrow[nf] + bkey[kq]);
#pragma unroll
            for (int nf = 0; nf < 6; ++nf)
                acc[nf] = __builtin_amdgcn_mfma_f32_16x16x32_bf16(
                    af, bf[nf], acc[nf], 0, 0, 0);
        }
    };

    // ---- prologue ----
    STAGE(0);
    asm volatile("s_waitcnt vmcnt(0)" ::: "memory");
    __builtin_amdgcn_s_barrier();

    // ---- main loop: 16 K-steps (m97 2-phase) ----
    for (int t = 0; t < 16; ++t) {
        if (t < 15) STAGE(t + 1);
        COMPUTE(t & 1);
        asm volatile("s_waitcnt vmcnt(0)" ::: "memory");
        __builtin_amdgcn_s_barrier();
    }

    // ---- epilogue: scatter to qs / kk / vt(bf16, transposed) ----
    const int b = row0 >> 11;
    const int rbase = row0 + wv * 16 + hi4 * 4;
#pragma unroll
    for (int nf = 0; nf < 6; ++nf) {
        int colg = cg * 96 + nf * 16 + r16;   // 0..191
        f32x4 v = acc[nf];
        if (colg < 64) {
#pragma unroll
            for (int j = 0; j < 4; ++j)
                qs[(size_t)(rbase + j) * HD + colg] = f2b(v[j]);
        } else if (colg < 128) {
#pragma unroll
            for (int j = 0; j < 4; ++j)
                kk[(size_t)(rbase + j) * HD + (colg - 64)] = f2b(v[j]);
        } else {
            int d = colg - 128;
            union { ushort4 s; ushort u[4]; } pk;
#pragma unroll
            for (int j = 0; j < 4; ++j) pk.u[j] = f2b(v[j]);
            *(ushort4*)(&vt[((size_t)(b * 64 + d)) * NT + (rbase & (NT - 1))]) = pk.s;
        }
    }
}

// ---------------------------------------------------------------------------
// Kernel 2: causal flash attention. 4 waves/block, intra-block split-K:
// wave w handles k-tiles w, w+4, ... of its 32-row q-tile; partial
// (m,l,o) merged in LDS with exp2 rescaling. grid = 512, big tiles first.
// ---------------------------------------------------------------------------
__global__ __launch_bounds__(256) void attn(const ushort* __restrict__ qs,
                                            const ushort* __restrict__ kk,
                                            const ushort* __restrict__ vt,
                                            float* __restrict__ out) {
    __shared__ float ob[4][64][33];   // per-wave unnormalized O^T partials
    __shared__ float ml[4][2][32];    // per-wave m / lsum per q col

    const int bid  = blockIdx.x;
    const int b    = bid & 7;
    const int tile = 63 - (bid >> 3);          // big-first for balance
    const int tid  = threadIdx.x;
    const int wv   = tid >> 6;                 // 0..3  (k-split index)
    const int l    = tid & 63;
    const int qcol = l & 31;
    const int hi   = l >> 5;
    const int r0   = tile * 32;

    const ushort* qb = qs + ((size_t)(b * NT + r0)) * HD;
    const ushort* kb = kk + (size_t)b * NT * HD;
    const ushort* vb = vt + (size_t)b * HD * NT;

    s16x8 qf[4];
#pragma unroll
    for (int c = 0; c < 4; ++c)
        qf[c] = *(const s16x8*)(qb + (size_t)qcol * HD + c * 16 + hi * 8);

    f32x16 o0, o1;
#pragma unroll
    for (int i = 0; i < 16; ++i) { o0[i] = 0.f; o1[i] = 0.f; }
    float m = -3.0e30f, lsum = 0.f;

    if (wv <= tile) {
        s16x8 kf[4], vf[4];
        {
            const ushort* kr = kb + (size_t)(wv * 32 + qcol) * HD;
#pragma unroll
            for (int c = 0; c < 4; ++c)
                kf[c] = *(const s16x8*)(kr + c * 16 + hi * 8);
#pragma unroll
            for (int dt = 0; dt < 2; ++dt)
#pragma unroll
                for (int kc = 0; kc < 2; ++kc)
                    vf[dt * 2 + kc] = *(const s16x8*)(vb + (size_t)(dt * 32 + qcol) * NT
                                                      + wv * 32 + kc * 16 + hi * 8);
        }

        for (int kt = wv; kt <= tile; kt += 4) {
            // S^T = K . Q^T   (col = q, row-regs = k_local)
            f32x16 s;
#pragma unroll
            for (int i = 0; i < 16; ++i) s[i] = 0.f;
#pragma unroll
            for (int c = 0; c < 4; ++c)
                s = __builtin_amdgcn_mfma_f32_32x32x16_bf16(kf[c], qf[c], s, 0, 0, 0);

            // prefetch this wave's next K/V tiles (stride 4)
            s16x8 kfn[4], vfn[4];
            const bool more = (kt + 4 <= tile);
            if (more) {
                const ushort* kr = kb + (size_t)((kt + 4) * 32 + qcol) * HD;
#pragma unroll
                for (int c = 0; c < 4; ++c)
                    kfn[c] = *(const s16x8*)(kr + c * 16 + hi * 8);
#pragma unroll
                for (int dt = 0; dt < 2; ++dt)
#pragma unroll
                    for (int kc = 0; kc < 2; ++kc)
                        vfn[dt * 2 + kc] = *(const s16x8*)(vb + (size_t)(dt * 32 + qcol) * NT
                                                           + (kt + 4) * 32 + kc * 16 + hi * 8);
            }

            // online softmax (per-lane scalar state: one q per lane)
            const bool diag = (kt == tile);
            float p[16];
#pragma unroll
            for (int r = 0; r < 16; ++r) {
                int klocal = (r & 3) + 8 * (r >> 2) + 4 * hi;
                float sv = s[r];
                if (diag && klocal > qcol) sv = -3.0e30f;
                p[r] = sv;
            }
            float pmax = p[0];
#pragma unroll
            for (int r = 1; r < 16; ++r) pmax = fmaxf(pmax, p[r]);
            pmax = fmaxf(pmax, __shfl_xor(pmax, 32));
            float mnew = fmaxf(m, pmax);
            float corr = exp2f(m - mnew);
            m = mnew;
            float rs = 0.f;
#pragma unroll
            for (int r = 0; r < 16; ++r) { p[r] = exp2f(p[r] - mnew); rs += p[r]; }
            rs += __shfl_xor(rs, 32);
            lsum = lsum * corr + rs;
#pragma unroll
            for (int i = 0; i < 16; ++i) { o0[i] *= corr; o1[i] *= corr; }

            // P (f32, S^T layout) -> bf16 B-fragments via cvt_pk + lane^32 exchange
#pragma unroll
            for (int kc = 0; kc < 2; ++kc) {
                int pb = kc * 8;
                uint32_t a0 = cvt_pk_bf16(p[pb + 0], p[pb + 1]);
                uint32_t a1 = cvt_pk_bf16(p[pb + 2], p[pb + 3]);
                uint32_t b0 = cvt_pk_bf16(p[pb + 4], p[pb + 5]);
                uint32_t b1 = cvt_pk_bf16(p[pb + 6], p[pb + 7]);
                uint32_t a0x = __shfl_xor(a0, 32);
                uint32_t a1x = __shfl_xor(a1, 32);
                uint32_t b0x = __shfl_xor(b0, 32);
                uint32_t b1x = __shfl_xor(b1, 32);
                union { uint32_t w[4]; s16x8 v; } frag;
                frag.w[0] = hi ? b0x : a0;
                frag.w[1] = hi ? b1x : a1;
                frag.w[2] = hi ? b0  : a0x;
                frag.w[3] = hi ? b1  : a1x;
                o0 = __builtin_amdgcn_mfma_f32_32x32x16_bf16(vf[0 * 2 + kc], frag.v, o0, 0, 0, 0);
                o1 = __builtin_amdgcn_mfma_f32_32x32x16_bf16(vf[1 * 2 + kc], frag.v, o1, 0, 0, 0);
            }

            if (more) {
#pragma unroll
                for (int c = 0; c < 4; ++c) kf[c] = kfn[c];
#pragma unroll
                for (int c = 0; c < 4; ++c) vf[c] = vfn[c];
            }
        }
    }

    // --- write per-wave partials (unnormalized) ---
#pragma unroll
    for (int r = 0; r < 16; ++r) {
        int d = (r & 3) + 8 * (r >> 2) + 4 * hi;
        ob[wv][d][qcol]      = o0[r];
        ob[wv][d + 32][qcol] = o1[r];
    }
    if (hi == 0) {
        ml[wv][0][qcol] = m;
        ml[wv][1][qcol] = lsum;
    }
    __syncthreads();

    // --- merge 4 partials + coalesced f32 store ---
    // thread -> (q = tid>>3, d block of 8 at (tid&7)*8)
    const int q  = tid >> 3;
    const int j0 = (tid & 7) * 8;
    float mw[4];
#pragma unroll
    for (int w = 0; w < 4; ++w) mw[w] = ml[w][0][q];
    float M = fmaxf(fmaxf(mw[0], mw[1]), fmaxf(mw[2], mw[3]));
    float sw[4]; float L = 0.f;
#pragma unroll
    for (int w = 0; w < 4; ++w) {
        sw[w] = exp2f(mw[w] - M);
        L += sw[w] * ml[w][1][q];
    }
    float invL = 1.0f / L;
    float vals[8];
#pragma unroll
    for (int j = 0; j < 8; ++j) {
        int d = j0 + j;
        float acc = 0.f;
#pragma unroll
        for (int w = 0; w < 4; ++w) acc += sw[w] * ob[w][d][q];
        vals[j] = acc * invL;
    }
    float* orow = out + ((size_t)(b * NT + r0 + q)) * HD + j0;
    *(float4*)(orow)     = make_float4(vals[0], vals[1], vals[2], vals[3]);
    *(float4*)(orow + 4) = make_float4(vals[4], vals[5], vals[6], vals[7]);
}

// ---------------------------------------------------------------------------
extern "C" void kernel_launch(void* const* d_in, const int* in_sizes, int n_in,
                              void* d_out, int out_size, void* d_ws, size_t ws_size,
                              hipStream_t stream) {
    const float* x = (const float*)d_in[0];
    const float* W = (const float*)d_in[1];
    float* out = (float*)d_out;

    ushort* qs = (ushort*)d_ws;                 // [8][2048][64] bf16 (pre-scaled q)
    ushort* kk = qs + (size_t)NB * NT * HD;     // [8][2048][64]
    ushort* vt = kk + (size_t)NB * NT * HD;     // [8][64][2048]  (V transposed)
    ushort* wt = vt + (size_t)NB * NT * HD;     // [192][1024]    (W^T bf16)

    wprep<<<768, 256, 0, stream>>>(W, wt);
    qkv_gemm<<<512, 256, 0, stream>>>(x, wt, qs, kk, vt);
    attn<<<512, 256, 0, stream>>>(qs, kk, vt, out);
}

// Round 10
// 54.029 us; speedup vs baseline: 1.4802x; 1.0032x over previous
//
#include <hip/hip_runtime.h>
#include <stdint.h>

#define NB 8
#define NT 2048
#define NC 1024
#define HD 64

typedef __attribute__((ext_vector_type(8)))  short s16x8;
typedef __attribute__((ext_vector_type(4)))  float f32x4;
typedef __attribute__((ext_vector_type(16))) float f32x16;

__device__ inline ushort f2b(float f) {
    union { float f; uint32_t u; } c; c.f = f;
    uint32_t u = c.u;
    uint32_t r = (u + 0x7fffu + ((u >> 16) & 1u)) >> 16;   // RNE, finite inputs
    return (ushort)r;
}

__device__ inline uint32_t cvt_pk_bf16(float lo, float hi) {
    uint32_t r;
    asm("v_cvt_pk_bf16_f32 %0, %1, %2" : "=v"(r) : "v"(lo), "v"(hi));
    return r;
}

__device__ inline void gload_lds16(const void* gsrc, void* lds) {
    __builtin_amdgcn_global_load_lds(
        (const __attribute__((address_space(1))) void*)gsrc,
        (__attribute__((address_space(3))) void*)lds, 16, 0, 0);
}

// ---------------------------------------------------------------------------
// Kernel 0: W [1024][192] f32  ->  Wt [192][1024] bf16, q-cols pre-scaled by
// 0.125 * log2(e) so attention logits are already base-2.
// ---------------------------------------------------------------------------
__global__ __launch_bounds__(256) void wprep(const float* __restrict__ W,
                                             ushort* __restrict__ wt) {
    int tid = blockIdx.x * 256 + threadIdx.x;   // 192*1024 total
    int n = tid >> 10;          // 0..191 (output col of qkv)
    int k = tid & 1023;         // 0..1023
    float v = W[k * 192 + n];
    if (n < 64) v *= 0.125f * 1.4426950408889634f;
    wt[n * 1024 + k] = f2b(v);
}

// ---------------------------------------------------------------------------
// Kernel 1: qkv = x @ W.  BM=64, BN=96, BK=64, 4 waves, grid 512 (2 blk/CU).
// T14 + T3/T4 schedule: A reg-staged f32->bf16 (A rows are wave-private:
// loads, ds_writes and ds_reads all within the owning wave); W via
// global_load_lds into 4 LDS buffers (readers two barriers away = race-free).
// Counted s_waitcnt vmcnt(7) per step (7 vm-ops/stage uniform, depth-2),
// NEVER vmcnt(0) until the tail. Raw s_barrier + explicit lgkmcnt(0) only.
// A stored bf16 [64][128B] XOR-swizzled (slot ^= row&7) -> 1 read/frag,
// 2-way residual conflicts (free). 14 ds_read_b128 / 12 MFMA per wave/step.
// ---------------------------------------------------------------------------
__global__ __launch_bounds__(256, 2) void qkv_gemm(const float* __restrict__ x,
                                                   const ushort* __restrict__ wt,
                                                   ushort* __restrict__ qs,
                                                   ushort* __restrict__ kk,
                                                   ushort* __restrict__ vt) {
    __shared__ __align__(16) char Al[2][8192];    // [64 rows][8 slots x 16B] bf16
    __shared__ __align__(16) char Wl[4][12288];   // [96 rows][8 slots x 16B] bf16

    const int tid = threadIdx.x;
    const int wv  = tid >> 6;         // 0..3
    const int ls  = tid & 63;
    const int r16 = ls & 15;
    const int hi4 = ls >> 4;          // 0..3
    const int bid = blockIdx.x;
    const int rowtile = bid & 255;
    const int cg  = bid >> 8;         // 0/1: cols cg*96..+96
    const int row0 = rowtile * 64;

    // ---- A staging (reg-staged, wave-private rows wv*16..+16) ----
    const int arl = ls >> 2;          // row_local 0..15
    const int asl = ls & 3;           // base slot 0..3
    const float* pA = x + (size_t)(row0 + wv * 16 + arl) * NC + asl * 8;
    const int akey = arl & 7;
    const int awb0 = (wv * 16 + arl) * 128 + ((asl ^ akey) << 4);
    const int awb1 = (wv * 16 + arl) * 128 + (((asl + 4) ^ akey) << 4);

    // ---- W staging sources (gload_lds, contiguity-preserving swizzle) ----
    const ushort* wsrc[3];
#pragma unroll
    for (int j = 0; j < 3; ++j) {
        int n = wv * 24 + j * 8 + (ls >> 3);            // 0..95 local col
        int slot = (ls & 7) ^ (n & 7);
        wsrc[j] = wt + (size_t)(cg * 96 + n) * 1024 + slot * 8;
    }

    // ---- ds_read offsets ----
    const int key = r16 & 7;
    const int arow = wv * 16 + r16;
    int aoff[2];
#pragma unroll
    for (int kq = 0; kq < 2; ++kq)
        aoff[kq] = arow * 128 + (((kq * 4 + hi4) ^ key) << 4);
    int bnrow[6];
#pragma unroll
    for (int nf = 0; nf < 6; ++nf)
        bnrow[nf] = (nf * 16 + r16) * 128;
    int bkey[2];
#pragma unroll
    for (int kq = 0; kq < 2; ++kq)
        bkey[kq] = (((kq * 4 + hi4) ^ key) << 4);

    f32x4 acc[6];
#pragma unroll
    for (int j = 0; j < 6; ++j)
#pragma unroll
        for (int e = 0; e < 4; ++e) acc[j][e] = 0.f;

    float4 rA[2][4];   // two stages of A in regs (statically indexed)

#define STAGE_LOAD(T, P)                                                     \
    do {                                                                     \
        rA[P][0] = *(const float4*)(pA + (T) * 64);                          \
        rA[P][1] = *(const float4*)(pA + (T) * 64 + 4);                      \
        rA[P][2] = *(const float4*)(pA + (T) * 64 + 32);                     \
        rA[P][3] = *(const float4*)(pA + (T) * 64 + 36);                     \
        gload_lds16(wsrc[0] + (T) * 64, &Wl[(T) & 3][wv * 3072 + 0 * 1024]); \
        gload_lds16(wsrc[1] + (T) * 64, &Wl[(T) & 3][wv * 3072 + 1 * 1024]); \
        gload_lds16(wsrc[2] + (T) * 64, &Wl[(T) & 3][wv * 3072 + 2 * 1024]); \
    } while (0)

#define A_WRITE(BB, P)                                                       \
    do {                                                                     \
        union { uint32_t w[4]; s16x8 v; } p0, p1;                            \
        p0.w[0] = cvt_pk_bf16(rA[P][0].x, rA[P][0].y);                       \
        p0.w[1] = cvt_pk_bf16(rA[P][0].z, rA[P][0].w);                       \
        p0.w[2] = cvt_pk_bf16(rA[P][1].x, rA[P][1].y);                       \
        p0.w[3] = cvt_pk_bf16(rA[P][1].z, rA[P][1].w);                       \
        p1.w[0] = cvt_pk_bf16(rA[P][2].x, rA[P][2].y);                       \
        p1.w[1] = cvt_pk_bf16(rA[P][2].z, rA[P][2].w);                       \
        p1.w[2] = cvt_pk_bf16(rA[P][3].x, rA[P][3].y);                       \
        p1.w[3] = cvt_pk_bf16(rA[P][3].z, rA[P][3].w);                       \
        *(s16x8*)(&Al[BB][awb0]) = p0.v;                                     \
        *(s16x8*)(&Al[BB][awb1]) = p1.v;                                     \
    } while (0)

#define COMPUTE(AB, WB)                                                      \
    do {                                                                     \
        _Pragma("unroll")                                                    \
        for (int kq = 0; kq < 2; ++kq) {                                     \
            s16x8 af = *(const s16x8*)(&Al[AB][0] + aoff[kq]);               \
            s16x8 bf[6];                                                     \
            _Pragma("unroll")                                                \
            for (int nf = 0; nf < 6; ++nf)                                   \
                bf[nf] = *(const s16x8*)(&Wl[WB][0] + bnrow[nf] + bkey[kq]); \
            _Pragma("unroll")                                                \
            for (int nf = 0; nf < 6; ++nf)                                   \
                acc[nf] = __builtin_amdgcn_mfma_f32_16x16x32_bf16(           \
                    af, bf[nf], acc[nf], 0, 0, 0);                           \
        }                                                                    \
    } while (0)

    // ---- prologue ----
    STAGE_LOAD(0, 0);
    STAGE_LOAD(1, 1);
    asm volatile("s_waitcnt vmcnt(7)" ::: "memory");   // stage 0 landed
    A_WRITE(0, 0);
    asm volatile("s_waitcnt lgkmcnt(0)" ::: "memory");
    __builtin_amdgcn_s_barrier();

    // ---- main loop: 16 K-steps, counted vmcnt, no full drain ----
#pragma unroll
    for (int t = 0; t < 16; ++t) {
        if (t + 2 <= 15) {
            STAGE_LOAD(t + 2, t & 1);
            asm volatile("s_waitcnt vmcnt(7)" ::: "memory");   // stage t+1 done
        } else {
            asm volatile("s_waitcnt vmcnt(0)" ::: "memory");   // tail drain
        }
        if (t + 1 <= 15) A_WRITE((t + 1) & 1, (t + 1) & 1);
        asm volatile("s_waitcnt lgkmcnt(0)" ::: "memory");
        __builtin_amdgcn_s_barrier();
        COMPUTE(t & 1, t & 3);
    }
#undef STAGE_LOAD
#undef A_WRITE
#undef COMPUTE

    // ---- epilogue: scatter to qs / kk / vt(bf16, transposed) ----
    const int b = row0 >> 11;
    const int rbase = row0 + wv * 16 + hi4 * 4;
#pragma unroll
    for (int nf = 0; nf < 6; ++nf) {
        int colg = cg * 96 + nf * 16 + r16;   // 0..191
        f32x4 v = acc[nf];
        if (colg < 64) {
#pragma unroll
            for (int j = 0; j < 4; ++j)
                qs[(size_t)(rbase + j) * HD + colg] = f2b(v[j]);
        } else if (colg < 128) {
#pragma unroll
            for (int j = 0; j < 4; ++j)
                kk[(size_t)(rbase + j) * HD + (colg - 64)] = f2b(v[j]);
        } else {
            int d = colg - 128;
            union { ushort4 s; ushort u[4]; } pk;
#pragma unroll
            for (int j = 0; j < 4; ++j) pk.u[j] = f2b(v[j]);
            *(ushort4*)(&vt[((size_t)(b * 64 + d)) * NT + (rbase & (NT - 1))]) = pk.s;
        }
    }
}

// ---------------------------------------------------------------------------
// Kernel 2: causal flash attention. 4 waves/block, intra-block split-K:
// wave w handles k-tiles w, w+4, ... of its 32-row q-tile; partial
// (m,l,o) merged in LDS with exp2 rescaling. grid = 512, big tiles first.
// ---------------------------------------------------------------------------
__global__ __launch_bounds__(256) void attn(const ushort* __restrict__ qs,
                                            const ushort* __restrict__ kk,
                                            const ushort* __restrict__ vt,
                                            float* __restrict__ out) {
    __shared__ float ob[4][64][33];   // per-wave unnormalized O^T partials
    __shared__ float ml[4][2][32];    // per-wave m / lsum per q col

    const int bid  = blockIdx.x;
    const int b    = bid & 7;
    const int tile = 63 - (bid >> 3);          // big-first for balance
    const int tid  = threadIdx.x;
    const int wv   = tid >> 6;                 // 0..3  (k-split index)
    const int l    = tid & 63;
    const int qcol = l & 31;
    const int hi   = l >> 5;
    const int r0   = tile * 32;

    const ushort* qb = qs + ((size_t)(b * NT + r0)) * HD;
    const ushort* kb = kk + (size_t)b * NT * HD;
    const ushort* vb = vt + (size_t)b * HD * NT;

    s16x8 qf[4];
#pragma unroll
    for (int c = 0; c < 4; ++c)
        qf[c] = *(const s16x8*)(qb + (size_t)qcol * HD + c * 16 + hi * 8);

    f32x16 o0, o1;
#pragma unroll
    for (int i = 0; i < 16; ++i) { o0[i] = 0.f; o1[i] = 0.f; }
    float m = -3.0e30f, lsum = 0.f;

    if (wv <= tile) {
        s16x8 kf[4], vf[4];
        {
            const ushort* kr = kb + (size_t)(wv * 32 + qcol) * HD;
#pragma unroll
            for (int c = 0; c < 4; ++c)
                kf[c] = *(const s16x8*)(kr + c * 16 + hi * 8);
#pragma unroll
            for (int dt = 0; dt < 2; ++dt)
#pragma unroll
                for (int kc = 0; kc < 2; ++kc)
                    vf[dt * 2 + kc] = *(const s16x8*)(vb + (size_t)(dt * 32 + qcol) * NT
                                                      + wv * 32 + kc * 16 + hi * 8);
        }

        for (int kt = wv; kt <= tile; kt += 4) {
            // S^T = K . Q^T   (col = q, row-regs = k_local)
            f32x16 s;
#pragma unroll
            for (int i = 0; i < 16; ++i) s[i] = 0.f;
#pragma unroll
            for (int c = 0; c < 4; ++c)
                s = __builtin_amdgcn_mfma_f32_32x32x16_bf16(kf[c], qf[c], s, 0, 0, 0);

            // prefetch this wave's next K/V tiles (stride 4)
            s16x8 kfn[4], vfn[4];
            const bool more = (kt + 4 <= tile);
            if (more) {
                const ushort* kr = kb + (size_t)((kt + 4) * 32 + qcol) * HD;
#pragma unroll
                for (int c = 0; c < 4; ++c)
                    kfn[c] = *(const s16x8*)(kr + c * 16 + hi * 8);
#pragma unroll
                for (int dt = 0; dt < 2; ++dt)
#pragma unroll
                    for (int kc = 0; kc < 2; ++kc)
                        vfn[dt * 2 + kc] = *(const s16x8*)(vb + (size_t)(dt * 32 + qcol) * NT
                                                           + (kt + 4) * 32 + kc * 16 + hi * 8);
            }

            // online softmax (per-lane scalar state: one q per lane)
            const bool diag = (kt == tile);
            float p[16];
#pragma unroll
            for (int r = 0; r < 16; ++r) {
                int klocal = (r & 3) + 8 * (r >> 2) + 4 * hi;
                float sv = s[r];
                if (diag && klocal > qcol) sv = -3.0e30f;
                p[r] = sv;
            }
            float pmax = p[0];
#pragma unroll
            for (int r = 1; r < 16; ++r) pmax = fmaxf(pmax, p[r]);
            pmax = fmaxf(pmax, __shfl_xor(pmax, 32));
            float mnew = fmaxf(m, pmax);
            float corr = exp2f(m - mnew);
            m = mnew;
            float rs = 0.f;
#pragma unroll
            for (int r = 0; r < 16; ++r) { p[r] = exp2f(p[r] - mnew); rs += p[r]; }
            rs += __shfl_xor(rs, 32);
            lsum = lsum * corr + rs;
#pragma unroll
            for (int i = 0; i < 16; ++i) { o0[i] *= corr; o1[i] *= corr; }

            // P (f32, S^T layout) -> bf16 B-fragments via cvt_pk + lane^32 exchange
#pragma unroll
            for (int kc = 0; kc < 2; ++kc) {
                int pb = kc * 8;
                uint32_t a0 = cvt_pk_bf16(p[pb + 0], p[pb + 1]);
                uint32_t a1 = cvt_pk_bf16(p[pb + 2], p[pb + 3]);
                uint32_t b0 = cvt_pk_bf16(p[pb + 4], p[pb + 5]);
                uint32_t b1 = cvt_pk_bf16(p[pb + 6], p[pb + 7]);
                uint32_t a0x = __shfl_xor(a0, 32);
                uint32_t a1x = __shfl_xor(a1, 32);
                uint32_t b0x = __shfl_xor(b0, 32);
                uint32_t b1x = __shfl_xor(b1, 32);
                union { uint32_t w[4]; s16x8 v; } frag;
                frag.w[0] = hi ? b0x : a0;
                frag.w[1] = hi ? b1x : a1;
                frag.w[2] = hi ? b0  : a0x;
                frag.w[3] = hi ? b1  : a1x;
                o0 = __builtin_amdgcn_mfma_f32_32x32x16_bf16(vf[0 * 2 + kc], frag.v, o0, 0, 0, 0);
                o1 = __builtin_amdgcn_mfma_f32_32x32x16_bf16(vf[1 * 2 + kc], frag.v, o1, 0, 0, 0);
            }

            if (more) {
#pragma unroll
                for (int c = 0; c < 4; ++c) kf[c] = kfn[c];
#pragma unroll
                for (int c = 0; c < 4; ++c) vf[c] = vfn[c];
            }
        }
    }

    // --- write per-wave partials (unnormalized) ---
#pragma unroll
    for (int r = 0; r < 16; ++r) {
        int d = (r & 3) + 8 * (r >> 2) + 4 * hi;
        ob[wv][d][qcol]      = o0[r];
        ob[wv][d + 32][qcol] = o1[r];
    }
    if (hi == 0) {
        ml[wv][0][qcol] = m;
        ml[wv][1][qcol] = lsum;
    }
    __syncthreads();

    // --- merge 4 partials + coalesced f32 store ---
    // thread -> (q = tid>>3, d block of 8 at (tid&7)*8)
    const int q  = tid >> 3;
    const int j0 = (tid & 7) * 8;
    float mw[4];
#pragma unroll
    for (int w = 0; w < 4; ++w) mw[w] = ml[w][0][q];
    float M = fmaxf(fmaxf(mw[0], mw[1]), fmaxf(mw[2], mw[3]));
    float sw[4]; float L = 0.f;
#pragma unroll
    for (int w = 0; w < 4; ++w) {
        sw[w] = exp2f(mw[w] - M);
        L += sw[w] * ml[w][1][q];
    }
    float invL = 1.0f / L;
    float vals[8];
#pragma unroll
    for (int j = 0; j < 8; ++j) {
        int d = j0 + j;
        float acc = 0.f;
#pragma unroll
        for (int w = 0; w < 4; ++w) acc += sw[w] * ob[w][d][q];
        vals[j] = acc * invL;
    }
    float* orow = out + ((size_t)(b * NT + r0 + q)) * HD + j0;
    *(float4*)(orow)     = make_float4(vals[0], vals[1], vals[2], vals[3]);
    *(float4*)(orow + 4) = make_float4(vals[4], vals[5], vals[6], vals[7]);
}

// ---------------------------------------------------------------------------
extern "C" void kernel_launch(void* const* d_in, const int* in_sizes, int n_in,
                              void* d_out, int out_size, void* d_ws, size_t ws_size,
                              hipStream_t stream) {
    const float* x = (const float*)d_in[0];
    const float* W = (const float*)d_in[1];
    float* out = (float*)d_out;

    ushort* qs = (ushort*)d_ws;                 // [8][2048][64] bf16 (pre-scaled q)
    ushort* kk = qs + (size_t)NB * NT * HD;     // [8][2048][64]
    ushort* vt = kk + (size_t)NB * NT * HD;     // [8][64][2048]  (V transposed)
    ushort* wt = vt + (size_t)NB * NT * HD;     // [192][1024]    (W^T bf16)

    wprep<<<768, 256, 0, stream>>>(W, wt);
    qkv_gemm<<<512, 256, 0, stream>>>(x, wt, qs, kk, vt);
    attn<<<512, 256, 0, stream>>>(qs, kk, vt, out);
}

// Round 11
// 53.069 us; speedup vs baseline: 1.5070x; 1.0181x over previous
//
#include <hip/hip_runtime.h>
#include <stdint.h>

#define NB 8
#define NT 2048
#define NC 1024
#define HD 64

typedef __attribute__((ext_vector_type(8)))  short s16x8;
typedef __attribute__((ext_vector_type(4)))  float f32x4;
typedef __attribute__((ext_vector_type(16))) float f32x16;

__device__ inline ushort f2b(float f) {
    union { float f; uint32_t u; } c; c.f = f;
    uint32_t u = c.u;
    uint32_t r = (u + 0x7fffu + ((u >> 16) & 1u)) >> 16;   // RNE, finite inputs
    return (ushort)r;
}

__device__ inline uint32_t cvt_pk_bf16(float lo, float hi) {
    uint32_t r;
    asm("v_cvt_pk_bf16_f32 %0, %1, %2" : "=v"(r) : "v"(lo), "v"(hi));
    return r;
}

__device__ inline void gload_lds16(const void* gsrc, void* lds) {
    __builtin_amdgcn_global_load_lds(
        (const __attribute__((address_space(1))) void*)gsrc,
        (__attribute__((address_space(3))) void*)lds, 16, 0, 0);
}

// ---------------------------------------------------------------------------
// Kernel 0: W [1024][192] f32  ->  Wt [192][1024] bf16, q-cols pre-scaled by
// 0.125 * log2(e) so attention logits are already base-2.
// ---------------------------------------------------------------------------
__global__ __launch_bounds__(256) void wprep(const float* __restrict__ W,
                                             ushort* __restrict__ wt) {
    int tid = blockIdx.x * 256 + threadIdx.x;   // 192*1024 total
    int n = tid >> 10;          // 0..191 (output col of qkv)
    int k = tid & 1023;         // 0..1023
    float v = W[k * 192 + n];
    if (n < 64) v *= 0.125f * 1.4426950408889634f;
    wt[n * 1024 + k] = f2b(v);
}

// ---------------------------------------------------------------------------
// Kernel 1: qkv = x @ W.  TLP-first: BM=32, BN=96, BK=64, 4 waves, grid 1024
// (512 rowtiles x 2 cg), 40KB LDS -> 3-4 blocks/CU co-resident (16 waves/CU).
// Per-block schedule is deliberately simple (2 LDS buffers, vmcnt(0) ->
// barrier -> STAGE(t+1) -> COMPUTE(t)): a block's stall is covered by the
// OTHER co-resident blocks (m114 cross-block overlap), not by own-block
// pipelining. Staging = global_load_lds(16B), contiguity-preserving swizzle
// (R8-verified 0 conflicts). cg is the top grid bit: all cg=0 blocks
// dispatch first, W-slice (192KB) stays L2-resident per XCD.
// Wave (g,c): rows g*16..+16, cols c*48..+48; 6 MFMA 16x16x32 per step.
// ---------------------------------------------------------------------------
__global__ __launch_bounds__(256, 4) void qkv_gemm(const float* __restrict__ x,
                                                   const ushort* __restrict__ wt,
                                                   ushort* __restrict__ qs,
                                                   ushort* __restrict__ kk,
                                                   ushort* __restrict__ vt) {
    __shared__ __align__(16) char Al[2][8192];    // [32 rows][16 slots x 16B] f32
    __shared__ __align__(16) char Wl[2][12288];   // [96 rows][8 slots x 16B] bf16

    const int tid = threadIdx.x;
    const int wv  = tid >> 6;         // 0..3
    const int ls  = tid & 63;
    const int r16 = ls & 15;
    const int hi4 = ls >> 4;          // 0..3
    const int bid = blockIdx.x;
    const int rowtile = bid & 511;
    const int cg  = bid >> 9;         // 0/1: cols cg*96..+96
    const int row0 = rowtile * 32;
    const int g   = wv >> 1;          // rowgroup 0..1 (16 rows)
    const int c   = wv & 1;           // colgroup 0..1 (48 cols)

    // ---- A staging sources: 2 instrs/wave, each 4 rows x 256B ----
    const float* xsrc[2];
#pragma unroll
    for (int j = 0; j < 2; ++j) {
        int r = (wv * 2 + j) * 4 + (ls >> 4);           // 0..31
        int slot = (ls & 15) ^ (r & 7);                 // in-row swizzle
        xsrc[j] = x + (size_t)(row0 + r) * NC + slot * 4;
    }
    // ---- W staging sources: 3 instrs/wave, each 8 rows x 128B ----
    const ushort* wsrc[3];
#pragma unroll
    for (int j = 0; j < 3; ++j) {
        int n = (wv * 3 + j) * 8 + (ls >> 3);           // 0..95 local col
        int slot = (ls & 7) ^ (n & 7);
        wsrc[j] = wt + (size_t)(cg * 96 + n) * 1024 + slot * 8;
    }

    // ---- ds_read offsets ----
    const int key = r16 & 7;
    const int arow = g * 16 + r16;
    int aoff[2];                                        // a1 = a0 ^ 16
#pragma unroll
    for (int kq = 0; kq < 2; ++kq)
        aoff[kq] = arow * 256 + (((kq * 8 + hi4 * 2) ^ key) << 4);
    int bnrow[3];
#pragma unroll
    for (int nf = 0; nf < 3; ++nf)
        bnrow[nf] = (c * 48 + nf * 16 + r16) * 128;
    int bkey[2];
#pragma unroll
    for (int kq = 0; kq < 2; ++kq)
        bkey[kq] = (((kq * 4 + hi4) ^ key) << 4);

    f32x4 acc[3];
#pragma unroll
    for (int j = 0; j < 3; ++j)
#pragma unroll
        for (int e = 0; e < 4; ++e) acc[j][e] = 0.f;

    auto STAGE = [&](int t) {
        int bb = t & 1;
#pragma unroll
        for (int j = 0; j < 2; ++j)
            gload_lds16(xsrc[j] + t * 64, &Al[bb][(wv * 2 + j) * 1024]);
#pragma unroll
        for (int j = 0; j < 3; ++j)
            gload_lds16(wsrc[j] + t * 64, &Wl[bb][(wv * 3 + j) * 1024]);
    };

    auto COMPUTE = [&](int bb) {
#pragma unroll
        for (int kq = 0; kq < 2; ++kq) {
            float4 a0 = *(const float4*)(&Al[bb][0] + aoff[kq]);
            float4 a1 = *(const float4*)(&Al[bb][0] + (aoff[kq] ^ 16));
            union { uint32_t w[4]; s16x8 v; } pk;
            pk.w[0] = cvt_pk_bf16(a0.x, a0.y);
            pk.w[1] = cvt_pk_bf16(a0.z, a0.w);
            pk.w[2] = cvt_pk_bf16(a1.x, a1.y);
            pk.w[3] = cvt_pk_bf16(a1.z, a1.w);
            s16x8 af = pk.v;
            s16x8 bf[3];
#pragma unroll
            for (int nf = 0; nf < 3; ++nf)
                bf[nf] = *(const s16x8*)(&Wl[bb][0] + bnrow[nf] + bkey[kq]);
#pragma unroll
            for (int nf = 0; nf < 3; ++nf)
                acc[nf] = __builtin_amdgcn_mfma_f32_16x16x32_bf16(
                    af, bf[nf], acc[nf], 0, 0, 0);
        }
    };

    // ---- prologue ----
    STAGE(0);

    // ---- main loop: 16 K-steps ----
    for (int t = 0; t < 16; ++t) {
        asm volatile("s_waitcnt vmcnt(0)" ::: "memory");   // stage t landed
        __builtin_amdgcn_s_barrier();                      // buf[t^1] readers done
        if (t < 15) STAGE(t + 1);
        COMPUTE(t & 1);
    }

    // ---- epilogue: scatter to qs / kk / vt(bf16, transposed) ----
    const int b = row0 >> 11;
    const int rbase = row0 + g * 16 + hi4 * 4;
#pragma unroll
    for (int nf = 0; nf < 3; ++nf) {
        int colg = cg * 96 + c * 48 + nf * 16 + r16;   // 0..191
        f32x4 v = acc[nf];
        if (colg < 64) {
#pragma unroll
            for (int j = 0; j < 4; ++j)
                qs[(size_t)(rbase + j) * HD + colg] = f2b(v[j]);
        } else if (colg < 128) {
#pragma unroll
            for (int j = 0; j < 4; ++j)
                kk[(size_t)(rbase + j) * HD + (colg - 64)] = f2b(v[j]);
        } else {
            int d = colg - 128;
            union { ushort4 s; ushort u[4]; } pk;
#pragma unroll
            for (int j = 0; j < 4; ++j) pk.u[j] = f2b(v[j]);
            *(ushort4*)(&vt[((size_t)(b * 64 + d)) * NT + (rbase & (NT - 1))]) = pk.s;
        }
    }
}

// ---------------------------------------------------------------------------
// Kernel 2: causal flash attention. 4 waves/block, intra-block split-K:
// wave w handles k-tiles w, w+4, ... of its 32-row q-tile; partial
// (m,l,o) merged in LDS with exp2 rescaling. grid = 512, big tiles first.
// ---------------------------------------------------------------------------
__global__ __launch_bounds__(256) void attn(const ushort* __restrict__ qs,
                                            const ushort* __restrict__ kk,
                                            const ushort* __restrict__ vt,
                                            float* __restrict__ out) {
    __shared__ float ob[4][64][33];   // per-wave unnormalized O^T partials
    __shared__ float ml[4][2][32];    // per-wave m / lsum per q col

    const int bid  = blockIdx.x;
    const int b    = bid & 7;
    const int tile = 63 - (bid >> 3);          // big-first for balance
    const int tid  = threadIdx.x;
    const int wv   = tid >> 6;                 // 0..3  (k-split index)
    const int l    = tid & 63;
    const int qcol = l & 31;
    const int hi   = l >> 5;
    const int r0   = tile * 32;

    const ushort* qb = qs + ((size_t)(b * NT + r0)) * HD;
    const ushort* kb = kk + (size_t)b * NT * HD;
    const ushort* vb = vt + (size_t)b * HD * NT;

    s16x8 qf[4];
#pragma unroll
    for (int c = 0; c < 4; ++c)
        qf[c] = *(const s16x8*)(qb + (size_t)qcol * HD + c * 16 + hi * 8);

    f32x16 o0, o1;
#pragma unroll
    for (int i = 0; i < 16; ++i) { o0[i] = 0.f; o1[i] = 0.f; }
    float m = -3.0e30f, lsum = 0.f;

    if (wv <= tile) {
        s16x8 kf[4], vf[4];
        {
            const ushort* kr = kb + (size_t)(wv * 32 + qcol) * HD;
#pragma unroll
            for (int c = 0; c < 4; ++c)
                kf[c] = *(const s16x8*)(kr + c * 16 + hi * 8);
#pragma unroll
            for (int dt = 0; dt < 2; ++dt)
#pragma unroll
                for (int kc = 0; kc < 2; ++kc)
                    vf[dt * 2 + kc] = *(const s16x8*)(vb + (size_t)(dt * 32 + qcol) * NT
                                                      + wv * 32 + kc * 16 + hi * 8);
        }

        for (int kt = wv; kt <= tile; kt += 4) {
            // S^T = K . Q^T   (col = q, row-regs = k_local)
            f32x16 s;
#pragma unroll
            for (int i = 0; i < 16; ++i) s[i] = 0.f;
#pragma unroll
            for (int c = 0; c < 4; ++c)
                s = __builtin_amdgcn_mfma_f32_32x32x16_bf16(kf[c], qf[c], s, 0, 0, 0);

            // prefetch this wave's next K/V tiles (stride 4)
            s16x8 kfn[4], vfn[4];
            const bool more = (kt + 4 <= tile);
            if (more) {
                const ushort* kr = kb + (size_t)((kt + 4) * 32 + qcol) * HD;
#pragma unroll
                for (int c = 0; c < 4; ++c)
                    kfn[c] = *(const s16x8*)(kr + c * 16 + hi * 8);
#pragma unroll
                for (int dt = 0; dt < 2; ++dt)
#pragma unroll
                    for (int kc = 0; kc < 2; ++kc)
                        vfn[dt * 2 + kc] = *(const s16x8*)(vb + (size_t)(dt * 32 + qcol) * NT
                                                           + (kt + 4) * 32 + kc * 16 + hi * 8);
            }

            // online softmax (per-lane scalar state: one q per lane)
            const bool diag = (kt == tile);
            float p[16];
#pragma unroll
            for (int r = 0; r < 16; ++r) {
                int klocal = (r & 3) + 8 * (r >> 2) + 4 * hi;
                float sv = s[r];
                if (diag && klocal > qcol) sv = -3.0e30f;
                p[r] = sv;
            }
            float pmax = p[0];
#pragma unroll
            for (int r = 1; r < 16; ++r) pmax = fmaxf(pmax, p[r]);
            pmax = fmaxf(pmax, __shfl_xor(pmax, 32));
            float mnew = fmaxf(m, pmax);
            float corr = exp2f(m - mnew);
            m = mnew;
            float rs = 0.f;
#pragma unroll
            for (int r = 0; r < 16; ++r) { p[r] = exp2f(p[r] - mnew); rs += p[r]; }
            rs += __shfl_xor(rs, 32);
            lsum = lsum * corr + rs;
#pragma unroll
            for (int i = 0; i < 16; ++i) { o0[i] *= corr; o1[i] *= corr; }

            // P (f32, S^T layout) -> bf16 B-fragments via cvt_pk + lane^32 exchange
#pragma unroll
            for (int kc = 0; kc < 2; ++kc) {
                int pb = kc * 8;
                uint32_t a0 = cvt_pk_bf16(p[pb + 0], p[pb + 1]);
                uint32_t a1 = cvt_pk_bf16(p[pb + 2], p[pb + 3]);
                uint32_t b0 = cvt_pk_bf16(p[pb + 4], p[pb + 5]);
                uint32_t b1 = cvt_pk_bf16(p[pb + 6], p[pb + 7]);
                uint32_t a0x = __shfl_xor(a0, 32);
                uint32_t a1x = __shfl_xor(a1, 32);
                uint32_t b0x = __shfl_xor(b0, 32);
                uint32_t b1x = __shfl_xor(b1, 32);
                union { uint32_t w[4]; s16x8 v; } frag;
                frag.w[0] = hi ? b0x : a0;
                frag.w[1] = hi ? b1x : a1;
                frag.w[2] = hi ? b0  : a0x;
                frag.w[3] = hi ? b1  : a1x;
                o0 = __builtin_amdgcn_mfma_f32_32x32x16_bf16(vf[0 * 2 + kc], frag.v, o0, 0, 0, 0);
                o1 = __builtin_amdgcn_mfma_f32_32x32x16_bf16(vf[1 * 2 + kc], frag.v, o1, 0, 0, 0);
            }

            if (more) {
#pragma unroll
                for (int c = 0; c < 4; ++c) kf[c] = kfn[c];
#pragma unroll
                for (int c = 0; c < 4; ++c) vf[c] = vfn[c];
            }
        }
    }

    // --- write per-wave partials (unnormalized) ---
#pragma unroll
    for (int r = 0; r < 16; ++r) {
        int d = (r & 3) + 8 * (r >> 2) + 4 * hi;
        ob[wv][d][qcol]      = o0[r];
        ob[wv][d + 32][qcol] = o1[r];
    }
    if (hi == 0) {
        ml[wv][0][qcol] = m;
        ml[wv][1][qcol] = lsum;
    }
    __syncthreads();

    // --- merge 4 partials + coalesced f32 store ---
    // thread -> (q = tid>>3, d block of 8 at (tid&7)*8)
    const int q  = tid >> 3;
    const int j0 = (tid & 7) * 8;
    float mw[4];
#pragma unroll
    for (int w = 0; w < 4; ++w) mw[w] = ml[w][0][q];
    float M = fmaxf(fmaxf(mw[0], mw[1]), fmaxf(mw[2], mw[3]));
    float sw[4]; float L = 0.f;
#pragma unroll
    for (int w = 0; w < 4; ++w) {
        sw[w] = exp2f(mw[w] - M);
        L += sw[w] * ml[w][1][q];
    }
    float invL = 1.0f / L;
    float vals[8];
#pragma unroll
    for (int j = 0; j < 8; ++j) {
        int d = j0 + j;
        float acc = 0.f;
#pragma unroll
        for (int w = 0; w < 4; ++w) acc += sw[w] * ob[w][d][q];
        vals[j] = acc * invL;
    }
    float* orow = out + ((size_t)(b * NT + r0 + q)) * HD + j0;
    *(float4*)(orow)     = make_float4(vals[0], vals[1], vals[2], vals[3]);
    *(float4*)(orow + 4) = make_float4(vals[4], vals[5], vals[6], vals[7]);
}

// ---------------------------------------------------------------------------
extern "C" void kernel_launch(void* const* d_in, const int* in_sizes, int n_in,
                              void* d_out, int out_size, void* d_ws, size_t ws_size,
                              hipStream_t stream) {
    const float* x = (const float*)d_in[0];
    const float* W = (const float*)d_in[1];
    float* out = (float*)d_out;

    ushort* qs = (ushort*)d_ws;                 // [8][2048][64] bf16 (pre-scaled q)
    ushort* kk = qs + (size_t)NB * NT * HD;     // [8][2048][64]
    ushort* vt = kk + (size_t)NB * NT * HD;     // [8][64][2048]  (V transposed)
    ushort* wt = vt + (size_t)NB * NT * HD;     // [192][1024]    (W^T bf16)

    wprep<<<768, 256, 0, stream>>>(W, wt);
    qkv_gemm<<<1024, 256, 0, stream>>>(x, wt, qs, kk, vt);
    attn<<<512, 256, 0, stream>>>(qs, kk, vt, out);
}

// Round 13
// 51.035 us; speedup vs baseline: 1.5671x; 1.0399x over previous
//
#include <hip/hip_runtime.h>
#include <stdint.h>

#define NB 8
#define NT 2048
#define NC 1024
#define HD 64

typedef __attribute__((ext_vector_type(8)))  short s16x8;
typedef __attribute__((ext_vector_type(4)))  float f32x4;
typedef __attribute__((ext_vector_type(16))) float f32x16;

__device__ inline ushort f2b(float f) {
    union { float f; uint32_t u; } c; c.f = f;
    uint32_t u = c.u;
    uint32_t r = (u + 0x7fffu + ((u >> 16) & 1u)) >> 16;   // RNE, finite inputs
    return (ushort)r;
}

__device__ inline uint32_t cvt_pk_bf16(float lo, float hi) {
    uint32_t r;
    asm("v_cvt_pk_bf16_f32 %0, %1, %2" : "=v"(r) : "v"(lo), "v"(hi));
    return r;
}

__device__ inline void gload_lds16(const void* gsrc, void* lds) {
    __builtin_amdgcn_global_load_lds(
        (const __attribute__((address_space(1))) void*)gsrc,
        (__attribute__((address_space(3))) void*)lds, 16, 0, 0);
}

// ---------------------------------------------------------------------------
// Kernel 0: W [1024][192] f32  ->  Wt [192][1024] bf16, q-cols pre-scaled by
// 0.125 * log2(e) so attention logits are already base-2.
// ---------------------------------------------------------------------------
__global__ __launch_bounds__(256) void wprep(const float* __restrict__ W,
                                             ushort* __restrict__ wt) {
    int tid = blockIdx.x * 256 + threadIdx.x;   // 192*1024 total
    int n = tid >> 10;          // 0..191 (output col of qkv)
    int k = tid & 1023;         // 0..1023
    float v = W[k * 192 + n];
    if (n < 64) v *= 0.125f * 1.4426950408889634f;
    wt[n * 1024 + k] = f2b(v);
}

// ---------------------------------------------------------------------------
// Kernel 1: qkv = x @ W.  [VERIFIED R10 VERSION — do not touch]
// BM=32, BN=96, BK=64, 4 waves, grid 1024 (512 rowtiles x 2 cg), 40KB LDS
// -> 4 blocks/CU. 2 LDS buffers, vmcnt(0) -> barrier -> STAGE(t+1) ->
// COMPUTE(t). global_load_lds(16B), contiguity-preserving swizzle.
// ---------------------------------------------------------------------------
__global__ __launch_bounds__(256, 4) void qkv_gemm(const float* __restrict__ x,
                                                   const ushort* __restrict__ wt,
                                                   ushort* __restrict__ qs,
                                                   ushort* __restrict__ kk,
                                                   ushort* __restrict__ vt) {
    __shared__ __align__(16) char Al[2][8192];    // [32 rows][16 slots x 16B] f32
    __shared__ __align__(16) char Wl[2][12288];   // [96 rows][8 slots x 16B] bf16

    const int tid = threadIdx.x;
    const int wv  = tid >> 6;         // 0..3
    const int ls  = tid & 63;
    const int r16 = ls & 15;
    const int hi4 = ls >> 4;          // 0..3
    const int bid = blockIdx.x;
    const int rowtile = bid & 511;
    const int cg  = bid >> 9;         // 0/1: cols cg*96..+96
    const int row0 = rowtile * 32;
    const int g   = wv >> 1;          // rowgroup 0..1 (16 rows)
    const int c   = wv & 1;           // colgroup 0..1 (48 cols)

    // ---- A staging sources: 2 instrs/wave, each 4 rows x 256B ----
    const float* xsrc[2];
#pragma unroll
    for (int j = 0; j < 2; ++j) {
        int r = (wv * 2 + j) * 4 + (ls >> 4);           // 0..31
        int slot = (ls & 15) ^ (r & 7);                 // in-row swizzle
        xsrc[j] = x + (size_t)(row0 + r) * NC + slot * 4;
    }
    // ---- W staging sources: 3 instrs/wave, each 8 rows x 128B ----
    const ushort* wsrc[3];
#pragma unroll
    for (int j = 0; j < 3; ++j) {
        int n = (wv * 3 + j) * 8 + (ls >> 3);           // 0..95 local col
        int slot = (ls & 7) ^ (n & 7);
        wsrc[j] = wt + (size_t)(cg * 96 + n) * 1024 + slot * 8;
    }

    // ---- ds_read offsets ----
    const int key = r16 & 7;
    const int arow = g * 16 + r16;
    int aoff[2];                                        // a1 = a0 ^ 16
#pragma unroll
    for (int kq = 0; kq < 2; ++kq)
        aoff[kq] = arow * 256 + (((kq * 8 + hi4 * 2) ^ key) << 4);
    int bnrow[3];
#pragma unroll
    for (int nf = 0; nf < 3; ++nf)
        bnrow[nf] = (c * 48 + nf * 16 + r16) * 128;
    int bkey[2];
#pragma unroll
    for (int kq = 0; kq < 2; ++kq)
        bkey[kq] = (((kq * 4 + hi4) ^ key) << 4);

    f32x4 acc[3];
#pragma unroll
    for (int j = 0; j < 3; ++j)
#pragma unroll
        for (int e = 0; e < 4; ++e) acc[j][e] = 0.f;

    auto STAGE = [&](int t) {
        int bb = t & 1;
#pragma unroll
        for (int j = 0; j < 2; ++j)
            gload_lds16(xsrc[j] + t * 64, &Al[bb][(wv * 2 + j) * 1024]);
#pragma unroll
        for (int j = 0; j < 3; ++j)
            gload_lds16(wsrc[j] + t * 64, &Wl[bb][(wv * 3 + j) * 1024]);
    };

    auto COMPUTE = [&](int bb) {
#pragma unroll
        for (int kq = 0; kq < 2; ++kq) {
            float4 a0 = *(const float4*)(&Al[bb][0] + aoff[kq]);
            float4 a1 = *(const float4*)(&Al[bb][0] + (aoff[kq] ^ 16));
            union { uint32_t w[4]; s16x8 v; } pk;
            pk.w[0] = cvt_pk_bf16(a0.x, a0.y);
            pk.w[1] = cvt_pk_bf16(a0.z, a0.w);
            pk.w[2] = cvt_pk_bf16(a1.x, a1.y);
            pk.w[3] = cvt_pk_bf16(a1.z, a1.w);
            s16x8 af = pk.v;
            s16x8 bf[3];
#pragma unroll
            for (int nf = 0; nf < 3; ++nf)
                bf[nf] = *(const s16x8*)(&Wl[bb][0] + bnrow[nf] + bkey[kq]);
#pragma unroll
            for (int nf = 0; nf < 3; ++nf)
                acc[nf] = __builtin_amdgcn_mfma_f32_16x16x32_bf16(
                    af, bf[nf], acc[nf], 0, 0, 0);
        }
    };

    // ---- prologue ----
    STAGE(0);

    // ---- main loop: 16 K-steps ----
    for (int t = 0; t < 16; ++t) {
        asm volatile("s_waitcnt vmcnt(0)" ::: "memory");   // stage t landed
        __builtin_amdgcn_s_barrier();                      // buf[t^1] readers done
        if (t < 15) STAGE(t + 1);
        COMPUTE(t & 1);
    }

    // ---- epilogue: scatter to qs / kk / vt(bf16, transposed) ----
    const int b = row0 >> 11;
    const int rbase = row0 + g * 16 + hi4 * 4;
#pragma unroll
    for (int nf = 0; nf < 3; ++nf) {
        int colg = cg * 96 + c * 48 + nf * 16 + r16;   // 0..191
        f32x4 v = acc[nf];
        if (colg < 64) {
#pragma unroll
            for (int j = 0; j < 4; ++j)
                qs[(size_t)(rbase + j) * HD + colg] = f2b(v[j]);
        } else if (colg < 128) {
#pragma unroll
            for (int j = 0; j < 4; ++j)
                kk[(size_t)(rbase + j) * HD + (colg - 64)] = f2b(v[j]);
        } else {
            int d = colg - 128;
            union { ushort4 s; ushort u[4]; } pk;
#pragma unroll
            for (int j = 0; j < 4; ++j) pk.u[j] = f2b(v[j]);
            *(ushort4*)(&vt[((size_t)(b * 64 + d)) * NT + (rbase & (NT - 1))]) = pk.s;
        }
    }
}

// ---------------------------------------------------------------------------
// Kernel 2: causal flash attention. 8 waves/block, intra-block split-K:
// wave w handles k-tiles w, w+8, ... of its 32-row q-tile; partial
// (m,l,o) merged in LDS with exp2 rescaling. grid = 512, big tiles first.
// (Mechanical extension of the verified split-4 version.)
// ---------------------------------------------------------------------------
__global__ __launch_bounds__(512) void attn(const ushort* __restrict__ qs,
                                            const ushort* __restrict__ kk,
                                            const ushort* __restrict__ vt,
                                            float* __restrict__ out) {
    __shared__ float ob[8][64][33];   // per-wave unnormalized O^T partials
    __shared__ float ml[8][2][32];    // per-wave m / lsum per q col

    const int bid  = blockIdx.x;
    const int b    = bid & 7;
    const int tile = 63 - (bid >> 3);          // big-first for balance
    const int tid  = threadIdx.x;
    const int wv   = tid >> 6;                 // 0..7  (k-split index)
    const int l    = tid & 63;
    const int qcol = l & 31;
    const int hi   = l >> 5;
    const int r0   = tile * 32;

    const ushort* qb = qs + ((size_t)(b * NT + r0)) * HD;
    const ushort* kb = kk + (size_t)b * NT * HD;
    const ushort* vb = vt + (size_t)b * HD * NT;

    s16x8 qf[4];
#pragma unroll
    for (int c = 0; c < 4; ++c)
        qf[c] = *(const s16x8*)(qb + (size_t)qcol * HD + c * 16 + hi * 8);

    f32x16 o0, o1;
#pragma unroll
    for (int i = 0; i < 16; ++i) { o0[i] = 0.f; o1[i] = 0.f; }
    float m = -3.0e30f, lsum = 0.f;

    if (wv <= tile) {
        s16x8 kf[4], vf[4];
        {
            const ushort* kr = kb + (size_t)(wv * 32 + qcol) * HD;
#pragma unroll
            for (int c = 0; c < 4; ++c)
                kf[c] = *(const s16x8*)(kr + c * 16 + hi * 8);
#pragma unroll
            for (int dt = 0; dt < 2; ++dt)
#pragma unroll
                for (int kc = 0; kc < 2; ++kc)
                    vf[dt * 2 + kc] = *(const s16x8*)(vb + (size_t)(dt * 32 + qcol) * NT
                                                      + wv * 32 + kc * 16 + hi * 8);
        }

        for (int kt = wv; kt <= tile; kt += 8) {
            // S^T = K . Q^T   (col = q, row-regs = k_local)
            f32x16 s;
#pragma unroll
            for (int i = 0; i < 16; ++i) s[i] = 0.f;
#pragma unroll
            for (int c = 0; c < 4; ++c)
                s = __builtin_amdgcn_mfma_f32_32x32x16_bf16(kf[c], qf[c], s, 0, 0, 0);

            // prefetch this wave's next K/V tiles (stride 8)
            s16x8 kfn[4], vfn[4];
            const bool more = (kt + 8 <= tile);
            if (more) {
                const ushort* kr = kb + (size_t)((kt + 8) * 32 + qcol) * HD;
#pragma unroll
                for (int c = 0; c < 4; ++c)
                    kfn[c] = *(const s16x8*)(kr + c * 16 + hi * 8);
#pragma unroll
                for (int dt = 0; dt < 2; ++dt)
#pragma unroll
                    for (int kc = 0; kc < 2; ++kc)
                        vfn[dt * 2 + kc] = *(const s16x8*)(vb + (size_t)(dt * 32 + qcol) * NT
                                                           + (kt + 8) * 32 + kc * 16 + hi * 8);
            }

            // online softmax (per-lane scalar state: one q per lane)
            const bool diag = (kt == tile);
            float p[16];
#pragma unroll
            for (int r = 0; r < 16; ++r) {
                int klocal = (r & 3) + 8 * (r >> 2) + 4 * hi;
                float sv = s[r];
                if (diag && klocal > qcol) sv = -3.0e30f;
                p[r] = sv;
            }
            float pmax = p[0];
#pragma unroll
            for (int r = 1; r < 16; ++r) pmax = fmaxf(pmax, p[r]);
            pmax = fmaxf(pmax, __shfl_xor(pmax, 32));
            float mnew = fmaxf(m, pmax);
            float corr = exp2f(m - mnew);
            m = mnew;
            float rs = 0.f;
#pragma unroll
            for (int r = 0; r < 16; ++r) { p[r] = exp2f(p[r] - mnew); rs += p[r]; }
            rs += __shfl_xor(rs, 32);
            lsum = lsum * corr + rs;
#pragma unroll
            for (int i = 0; i < 16; ++i) { o0[i] *= corr; o1[i] *= corr; }

            // P (f32, S^T layout) -> bf16 B-fragments via cvt_pk + lane^32 exchange
#pragma unroll
            for (int kc = 0; kc < 2; ++kc) {
                int pb = kc * 8;
                uint32_t a0 = cvt_pk_bf16(p[pb + 0], p[pb + 1]);
                uint32_t a1 = cvt_pk_bf16(p[pb + 2], p[pb + 3]);
                uint32_t b0 = cvt_pk_bf16(p[pb + 4], p[pb + 5]);
                uint32_t b1 = cvt_pk_bf16(p[pb + 6], p[pb + 7]);
                uint32_t a0x = __shfl_xor(a0, 32);
                uint32_t a1x = __shfl_xor(a1, 32);
                uint32_t b0x = __shfl_xor(b0, 32);
                uint32_t b1x = __shfl_xor(b1, 32);
                union { uint32_t w[4]; s16x8 v; } frag;
                frag.w[0] = hi ? b0x : a0;
                frag.w[1] = hi ? b1x : a1;
                frag.w[2] = hi ? b0  : a0x;
                frag.w[3] = hi ? b1  : a1x;
                o0 = __builtin_amdgcn_mfma_f32_32x32x16_bf16(vf[0 * 2 + kc], frag.v, o0, 0, 0, 0);
                o1 = __builtin_amdgcn_mfma_f32_32x32x16_bf16(vf[1 * 2 + kc], frag.v, o1, 0, 0, 0);
            }

            if (more) {
#pragma unroll
                for (int c = 0; c < 4; ++c) kf[c] = kfn[c];
#pragma unroll
                for (int c = 0; c < 4; ++c) vf[c] = vfn[c];
            }
        }
    }

    // --- write per-wave partials (unnormalized) ---
#pragma unroll
    for (int r = 0; r < 16; ++r) {
        int d = (r & 3) + 8 * (r >> 2) + 4 * hi;
        ob[wv][d][qcol]      = o0[r];
        ob[wv][d + 32][qcol] = o1[r];
    }
    if (hi == 0) {
        ml[wv][0][qcol] = m;
        ml[wv][1][qcol] = lsum;
    }
    __syncthreads();

    // --- merge 8 partials + coalesced f32 store ---
    // thread -> (q = tid>>4, d block of 4 at (tid&15)*4)
    const int q  = tid >> 4;          // 0..31
    const int j0 = (tid & 15) * 4;    // 0..60
    float mwv[8];
#pragma unroll
    for (int w = 0; w < 8; ++w) mwv[w] = ml[w][0][q];
    float M = mwv[0];
#pragma unroll
    for (int w = 1; w < 8; ++w) M = fmaxf(M, mwv[w]);
    float sw[8]; float L = 0.f;
#pragma unroll
    for (int w = 0; w < 8; ++w) {
        sw[w] = exp2f(mwv[w] - M);
        L += sw[w] * ml[w][1][q];
    }
    float invL = 1.0f / L;
    float vals[4];
#pragma unroll
    for (int j = 0; j < 4; ++j) {
        int d = j0 + j;
        float acc = 0.f;
#pragma unroll
        for (int w = 0; w < 8; ++w) acc += sw[w] * ob[w][d][q];
        vals[j] = acc * invL;
    }
    float* orow = out + ((size_t)(b * NT + r0 + q)) * HD + j0;
    *(float4*)(orow) = make_float4(vals[0], vals[1], vals[2], vals[3]);
}

// ---------------------------------------------------------------------------
extern "C" void kernel_launch(void* const* d_in, const int* in_sizes, int n_in,
                              void* d_out, int out_size, void* d_ws, size_t ws_size,
                              hipStream_t stream) {
    const float* x = (const float*)d_in[0];
    const float* W = (const float*)d_in[1];
    float* out = (float*)d_out;

    ushort* qs = (ushort*)d_ws;                 // [8][2048][64] bf16 (pre-scaled q)
    ushort* kk = qs + (size_t)NB * NT * HD;     // [8][2048][64]
    ushort* vt = kk + (size_t)NB * NT * HD;     // [8][64][2048]  (V transposed)
    ushort* wt = vt + (size_t)NB * NT * HD;     // [192][1024]    (W^T bf16)

    wprep<<<768, 256, 0, stream>>>(W, wt);
    qkv_gemm<<<1024, 256, 0, stream>>>(x, wt, qs, kk, vt);
    attn<<<512, 512, 0, stream>>>(qs, kk, vt, out);
}